// Round 1
// baseline (284.822 us; speedup 1.0000x reference)
//
#include <hip/hip_runtime.h>
#include <hip/hip_bf16.h>

#define NTOK 197
#define NHEAD 10
#define XROW 1920

typedef __attribute__((ext_vector_type(8))) short short8;
typedef __attribute__((ext_vector_type(4))) float f32x4;

union S8U { short8 v; unsigned short u[8]; };

__device__ __forceinline__ unsigned short f2b(float f) {
    union { float f; unsigned int i; } a; a.f = f;
    unsigned int r = a.i + 0x7FFFu + ((a.i >> 16) & 1u);
    return (unsigned short)(r >> 16);
}

__device__ __forceinline__ short8 cvt8(const float* p) {
    const float4* s4 = (const float4*)p;
    float4 f0 = s4[0], f1 = s4[1];
    S8U t;
    t.u[0] = f2b(f0.x); t.u[1] = f2b(f0.y); t.u[2] = f2b(f0.z); t.u[3] = f2b(f0.w);
    t.u[4] = f2b(f1.x); t.u[5] = f2b(f1.y); t.u[6] = f2b(f1.z); t.u[7] = f2b(f1.w);
    return t.v;
}

// LDS layout (bytes):
//  A''  [208 rows][96 bf16 = 192B]   rows=i, cols 0..63 Q, 64..95 aug (wqv|wqh|qd0)
//  B''  [208 rows][96 bf16 = 192B]   rows=j, cols 0..63 K, 64..95 indicators
//  VT   [64  rows][256 bf16 = 512B]  rows=d, slots: 0..196 V[j][d], 197 vtv0+vth0,
//                                    198..226 vtv[1..29], 227..255 vth[1..29]  (XOR-swizzled)
//  Bm   [32  rows][224 bf16 = 448B]  bucket indicators (rows: 0..14 j/14, 15 j==0, 16..29 j%14)
//  P''  4 waves x [16 rows][256 bf16 = 512B] (XOR-swizzled); aliased by Vrow-temp and T early
#define OFF_A   0
#define OFF_B   39936
#define OFF_VT  79872
#define OFF_BM  112640
#define OFF_P   126976
#define LDS_TOTAL 159744

#define MFMA(a, b, c) __builtin_amdgcn_mfma_f32_16x16x32_bf16(a, b, c, 0, 0, 0)

__global__ __launch_bounds__(256)
void attn_super(const float* __restrict__ x,
                const float* __restrict__ ktv, const float* __restrict__ kth,
                const float* __restrict__ vtv, const float* __restrict__ vth,
                float* __restrict__ out)
{
    extern __shared__ char smem[];
    char* const As  = smem + OFF_A;
    char* const Bs  = smem + OFF_B;
    char* const VT  = smem + OFF_VT;
    char* const Bmm = smem + OFF_BM;
    char* const Pr  = smem + OFF_P;
    char* const Vrow = Pr;   // temp alias (staging only)
    char* const Tm   = Pr;   // temp alias (QD phase only)

    const int tid = threadIdx.x;
    const int bb = blockIdx.x / NHEAD;
    const int hh = blockIdx.x - bb * NHEAD;
    const float* const xq = x + (size_t)bb * NTOK * XROW + hh * 64;

    // ---------------- S0: stage A'', B'', Vrow, Bm, VT table slots ----------------
    #pragma unroll
    for (int it = 0; it < 10; ++it) {             // A'' : 208*12 = 2496 chunks
        int cid = tid + it * 256;
        if (cid < 2496) {
            int row = cid / 12, cc = cid - row * 12;
            S8U t;
            #pragma unroll
            for (int e = 0; e < 8; ++e) t.u[e] = 0;
            if (cc < 8 && row < NTOK) t.v = cvt8(xq + (size_t)row * XROW + cc * 8);
            *(short8*)(As + row * 192 + cc * 16) = t.v;
        }
    }
    #pragma unroll
    for (int it = 0; it < 10; ++it) {             // B'' : K + indicator columns
        int cid = tid + it * 256;
        if (cid < 2496) {
            int row = cid / 12, cc = cid - row * 12;
            S8U t;
            #pragma unroll
            for (int e = 0; e < 8; ++e) t.u[e] = 0;
            if (row < NTOK) {
                if (cc < 8) {
                    t.v = cvt8(xq + 640 + (size_t)row * XROW + cc * 8);
                } else {
                    #pragma unroll
                    for (int e = 0; e < 8; ++e) {
                        int kk = cc * 8 + e;      // 64..95
                        int on = 0;
                        if (kk <= 78)      on = (row >= 1) && (row / 14 == kk - 64);
                        else if (kk <= 92) on = (row >= 1) && (row % 14 == kk - 79);
                        else if (kk == 93) on = (row == 0);
                        t.u[e] = on ? 0x3F80 : 0;
                    }
                }
            }
            *(short8*)(Bs + row * 192 + cc * 16) = t.v;
        }
    }
    #pragma unroll
    for (int it = 0; it < 7; ++it) {              // Vrow temp : 197*8 = 1576 chunks
        int cid = tid + it * 256;
        if (cid < 1576) {
            int row = cid / 8, cc = cid - row * 8;
            short8 v = cvt8(xq + 1280 + (size_t)row * XROW + cc * 8);
            *(short8*)(Vrow + row * 128 + cc * 16) = v;
        }
    }
    #pragma unroll
    for (int it = 0; it < 4; ++it) {              // Bm : 32*28 = 896 chunks
        int cid = tid + it * 256;
        if (cid < 896) {
            int row = cid / 28, cc = cid - row * 28;
            S8U t;
            #pragma unroll
            for (int e = 0; e < 8; ++e) {
                int j = cc * 8 + e;
                int on = 0;
                if (j < NTOK) {
                    if (row <= 14)      on = (j >= 1) && (j / 14 == row);
                    else if (row == 15) on = (j == 0);
                    else if (row <= 29) on = (j >= 1) && (j % 14 == row - 16);
                }
                t.u[e] = on ? 0x3F80 : 0;
            }
            *(short8*)(Bmm + row * 448 + cc * 16) = t.v;
        }
    }
    {                                             // VT slots 197..255 (tables)
        int d = tid & 63, rr = tid >> 6;
        #pragma unroll
        for (int it = 0; it < 15; ++it) {
            int r = rr + it * 4;
            if (r < 59) {
                float v;
                if (r == 0)       v = vtv[d] + vth[d];
                else if (r <= 29) v = vtv[r * 64 + d];
                else              v = vth[(r - 29) * 64 + d];
                int slot = 197 + r;
                int ch = (slot >> 3) ^ (d & 7);
                *(unsigned short*)(VT + d * 512 + ch * 16 + (slot & 7) * 2) = f2b(v);
            }
        }
    }
    __syncthreads();
    // ---------------- S1: transpose Vrow -> VT slots 0..196 ----------------
    #pragma unroll
    for (int it = 0; it < 7; ++it) {
        int cid = tid + it * 256;
        if (cid < 1576) {
            int j = cid / 8, cc = cid - j * 8;
            S8U t; t.v = *(const short8*)(Vrow + j * 128 + cc * 16);
            #pragma unroll
            for (int e = 0; e < 8; ++e) {
                int d = cc * 8 + e;
                int ch = (j >> 3) ^ (d & 7);
                *(unsigned short*)(VT + d * 512 + ch * 16 + (j & 7) * 2) = t.u[e];
            }
        }
    }
    __syncthreads();
    // ---------------- S2: stage T (QD tables) ----------------
    #pragma unroll
    for (int it = 0; it < 2; ++it) {
        int cid = tid + it * 256;                 // 64*8 = 512 chunks
        int row = cid / 8, cc = cid - row * 8;
        S8U t;
        #pragma unroll
        for (int e = 0; e < 8; ++e) {
            float v = 0.f;
            int dc = cc * 8 + e;
            if (row <= 29)      v = ktv[row * 64 + dc];
            else if (row <= 59) v = kth[(row - 30) * 64 + dc];
            else if (row == 60) v = ktv[dc] + kth[dc];
            t.u[e] = f2b(v);
        }
        *(short8*)(Tm + row * 128 + ((cc ^ (row & 7)) * 16)) = t.v;
    }
    __syncthreads();

    const int w  = tid >> 6, l = tid & 63;
    const int lm = l & 15,  lg = l >> 4;
    const f32x4 fzero = {0.f, 0.f, 0.f, 0.f};

    // ---------------- QD GEMM + scatter wq into A'' aug columns ----------------
    for (int rt = w; rt < 13; rt += 4) {
        f32x4 qd[4];
        #pragma unroll
        for (int n = 0; n < 4; ++n) qd[n] = fzero;
        #pragma unroll
        for (int s = 0; s < 2; ++s) {
            short8 af = *(const short8*)(As + (rt * 16 + lm) * 192 + (s * 4 + lg) * 16);
            #pragma unroll
            for (int n = 0; n < 4; ++n) {
                int tr = n * 16 + lm;
                short8 tf = *(const short8*)(Tm + tr * 128 + (((s * 4 + lg) ^ (tr & 7)) * 16));
                qd[n] = MFMA(af, tf, qd[n]);
            }
        }
        #pragma unroll
        for (int n = 0; n < 4; ++n) {
            int r = n * 16 + lm;
            #pragma unroll
            for (int reg = 0; reg < 4; ++reg) {
                int i = rt * 16 + lg * 4 + reg;
                if (i == 0) continue;
                int col = -1;
                if (r <= 29)      { int c = r - 15 + i / 14; if (c >= 0 && c <= 14) col = 64 + c; }
                else if (r <= 59) { int c = r - 45 + i % 14; if (c >= 0 && c <= 13) col = 79 + c; }
                else if (r == 60) col = 93;
                if (col >= 0)
                    *(unsigned short*)(As + i * 192 + col * 2) = f2b(qd[n][reg]);
            }
        }
        if (rt == 0 && l == 12) {                 // row 0: constant bias qdv[0]+qdh[0]
            unsigned short v = f2b(qd[3][0]);
            #pragma unroll
            for (int c = 0; c <= 14; ++c) *(unsigned short*)(As + (64 + c) * 2) = v;
            *(unsigned short*)(As + 93 * 2) = v;
        }
    }
    __syncthreads();

    // ---------------- main loop: per 16-row tile ----------------
    char* const Pw = Pr + w * 8192;
    for (int rt = w; rt < 13; rt += 4) {
        // S = A'' . B''^T  (K = 96)
        short8 af[3];
        #pragma unroll
        for (int s = 0; s < 3; ++s)
            af[s] = *(const short8*)(As + (rt * 16 + lm) * 192 + (s * 4 + lg) * 16);
        f32x4 acc[13];
        #pragma unroll
        for (int ct = 0; ct < 13; ++ct) acc[ct] = fzero;
        #pragma unroll
        for (int ct = 0; ct < 13; ++ct) {
            #pragma unroll
            for (int s = 0; s < 3; ++s) {
                short8 bf = *(const short8*)(Bs + (ct * 16 + lm) * 192 + (s * 4 + lg) * 16);
                acc[ct] = MFMA(af[s], bf, acc[ct]);
            }
        }
        // scale, mask cols >= 197, softmax (rows live in 16-lane groups)
        #pragma unroll
        for (int ct = 0; ct < 13; ++ct) {
            acc[ct][0] *= 0.125f; acc[ct][1] *= 0.125f;
            acc[ct][2] *= 0.125f; acc[ct][3] *= 0.125f;
        }
        if (lm >= 5) {
            acc[12][0] = -INFINITY; acc[12][1] = -INFINITY;
            acc[12][2] = -INFINITY; acc[12][3] = -INFINITY;
        }
        #pragma unroll
        for (int reg = 0; reg < 4; ++reg) {
            float m = acc[0][reg];
            #pragma unroll
            for (int ct = 1; ct < 13; ++ct) m = fmaxf(m, acc[ct][reg]);
            m = fmaxf(m, __shfl_xor(m, 1)); m = fmaxf(m, __shfl_xor(m, 2));
            m = fmaxf(m, __shfl_xor(m, 4)); m = fmaxf(m, __shfl_xor(m, 8));
            float ss = 0.f;
            #pragma unroll
            for (int ct = 0; ct < 13; ++ct) {
                float p = __expf(acc[ct][reg] - m);
                acc[ct][reg] = p; ss += p;
            }
            ss += __shfl_xor(ss, 1); ss += __shfl_xor(ss, 2);
            ss += __shfl_xor(ss, 4); ss += __shfl_xor(ss, 8);
            float inv = 1.0f / ss;
            #pragma unroll
            for (int ct = 0; ct < 13; ++ct) acc[ct][reg] *= inv;
        }
        // write P (bf16, swizzled); cols 197..207 are exact zeros (mask)
        #pragma unroll
        for (int ct = 0; ct < 13; ++ct) {
            int colc = ct * 16 + lm;
            #pragma unroll
            for (int reg = 0; reg < 4; ++reg) {
                int row = lg * 4 + reg;
                *(unsigned short*)(Pw + row * 512 + (((colc >> 3) ^ (row & 7)) * 16)
                                   + (colc & 7) * 2) = f2b(acc[ct][reg]);
            }
        }
        // zero aug chunks 26..31 (slots 208..255)
        #pragma unroll
        for (int zz = 0; zz < 2; ++zz) {
            int z = l + zz * 64;
            if (z < 96) {
                int row = z / 6, ch = 26 + (z - row * 6);
                S8U zv;
                #pragma unroll
                for (int e = 0; e < 8; ++e) zv.u[e] = 0;
                *(short8*)(Pw + row * 512 + ((ch ^ (row & 7)) * 16)) = zv.v;
            }
        }
        __threadfence_block();
        // bucket GEMM: BC = P . Bm^T  (K = 224)
        f32x4 bc[2]; bc[0] = fzero; bc[1] = fzero;
        #pragma unroll
        for (int s = 0; s < 7; ++s) {
            short8 pf = *(const short8*)(Pw + lm * 512 + (((s * 4 + lg) ^ (lm & 7)) * 16));
            #pragma unroll
            for (int n = 0; n < 2; ++n) {
                short8 bmf = *(const short8*)(Bmm + (n * 16 + lm) * 448 + (s * 4 + lg) * 16);
                bc[n] = MFMA(pf, bmf, bc[n]);
            }
        }
        // scatter buckets into P'' aug slots (shifted by i/14, i%14)
        #pragma unroll
        for (int n = 0; n < 2; ++n) {
            int t = n * 16 + lm;
            #pragma unroll
            for (int reg = 0; reg < 4; ++reg) {
                int row = lg * 4 + reg;
                int i = rt * 16 + row;
                if (i == 0) {
                    if (t == 15)   // sum(p) == 1 -> coeff 1.0 on (vtv[0]+vth[0])
                        *(unsigned short*)(Pw + (24 * 16) + (197 & 7) * 2) = 0x3F80;
                    continue;
                }
                if (i >= NTOK) continue;
                int slot = -1;
                if (t <= 14)      slot = 197 + (t + 15 - i / 14);
                else if (t == 15) slot = 197;
                else if (t <= 29) slot = 226 + ((t - 16) + 15 - i % 14);
                if (slot >= 0)
                    *(unsigned short*)(Pw + row * 512 + (((slot >> 3) ^ (row & 7)) * 16)
                                       + (slot & 7) * 2) = f2b(bc[n][reg]);
            }
        }
        __threadfence_block();
        // PV GEMM: O = P'' . V''  (K = 256)
        f32x4 o[4];
        #pragma unroll
        for (int nv = 0; nv < 4; ++nv) o[nv] = fzero;
        #pragma unroll
        for (int s = 0; s < 8; ++s) {
            short8 pf = *(const short8*)(Pw + lm * 512 + (((s * 4 + lg) ^ (lm & 7)) * 16));
            #pragma unroll
            for (int nv = 0; nv < 4; ++nv) {
                int vr = nv * 16 + lm;
                short8 vf = *(const short8*)(VT + vr * 512 + (((s * 4 + lg) ^ (vr & 7)) * 16));
                o[nv] = MFMA(pf, vf, o[nv]);
            }
        }
        // store
        #pragma unroll
        for (int reg = 0; reg < 4; ++reg) {
            int i = rt * 16 + lg * 4 + reg;
            if (i < NTOK) {
                float* dst = out + (size_t)bb * (NTOK * 640) + (size_t)i * 640 + hh * 64 + lm;
                #pragma unroll
                for (int nv = 0; nv < 4; ++nv) dst[nv * 16] = o[nv][reg];
            }
        }
    }
}

extern "C" void kernel_launch(void* const* d_in, const int* in_sizes, int n_in,
                              void* d_out, int out_size, void* d_ws, size_t ws_size,
                              hipStream_t stream) {
    const float* x   = (const float*)d_in[0];
    const float* ktv = (const float*)d_in[1];
    const float* kth = (const float*)d_in[2];
    const float* vtv = (const float*)d_in[3];
    const float* vth = (const float*)d_in[4];
    float* out = (float*)d_out;
    (void)hipFuncSetAttribute((const void*)attn_super,
                              hipFuncAttributeMaxDynamicSharedMemorySize, LDS_TOTAL);
    attn_super<<<dim3(64 * NHEAD), dim3(256), LDS_TOTAL, stream>>>(x, ktv, kth, vtv, vth, out);
}

// Round 3
// 214.025 us; speedup vs baseline: 1.3308x; 1.3308x over previous
//
#include <hip/hip_runtime.h>
#include <hip/hip_bf16.h>

#define NTOK 197
#define NHEAD 10
#define XROW 1920

typedef __attribute__((ext_vector_type(8))) short short8;
typedef __attribute__((ext_vector_type(4))) float f32x4;

union S8U { short8 v; unsigned short u[8]; };

__device__ __forceinline__ unsigned short f2b(float f) {
    union { float f; unsigned int i; } a; a.f = f;
    unsigned int r = a.i + 0x7FFFu + ((a.i >> 16) & 1u);
    return (unsigned short)(r >> 16);
}

__device__ __forceinline__ short8 cvt8(const float* p) {
    const float4* s4 = (const float4*)p;
    float4 f0 = s4[0], f1 = s4[1];
    S8U t;
    t.u[0] = f2b(f0.x); t.u[1] = f2b(f0.y); t.u[2] = f2b(f0.z); t.u[3] = f2b(f0.w);
    t.u[4] = f2b(f1.x); t.u[5] = f2b(f1.y); t.u[6] = f2b(f1.z); t.u[7] = f2b(f1.w);
    return t.v;
}

// LDS layout (bytes), all fragment reads XOR-swizzled for uniform bank spread:
//  K    [208 rows][64 bf16 = 128B]  chunk' = cc ^ (row&7)
//  Ind  [208 rows][32 bf16 =  64B]  indicator cols 64..95, no swizzle (natural spread)
//  VT   [64  d   ][256 slots=512B]  slots 0..196 V^T, 197..255 v-tables; ch' = ch ^ (d&7)
//  T    [64  rows][64 bf16 = 128B]  QD tables (ktv|kth|ktv0+kth0); ch' = cc ^ (row&7)
//  Bm   [32  rows][256 col = 512B]  bucket indicators; ch' = cc ^ (row&7)
//  P    8 waves x [16 rows][512B]   per-wave P''; ch' = ch ^ (row&7); rows 0-1 alias aug buf
#define OFF_K   0
#define OFF_IND 26624
#define OFF_VT  39936
#define OFF_T   72704
#define OFF_BM  80896
#define OFF_P   97280
#define LDS_TOTAL 162816

#define MFMA(a, b, c) __builtin_amdgcn_mfma_f32_16x16x32_bf16(a, b, c, 0, 0, 0)

__global__ __launch_bounds__(512)
void attn_super(const float* __restrict__ x,
                const float* __restrict__ ktv, const float* __restrict__ kth,
                const float* __restrict__ vtv, const float* __restrict__ vth,
                float* __restrict__ out)
{
    extern __shared__ char smem[];
    char* const Ks   = smem + OFF_K;
    char* const Inds = smem + OFF_IND;
    char* const VT   = smem + OFF_VT;
    char* const Ts   = smem + OFF_T;
    char* const Bms  = smem + OFF_BM;
    char* const Pr   = smem + OFF_P;

    const int tid = threadIdx.x;
    const int bb = blockIdx.x / NHEAD;
    const int hh = blockIdx.x - bb * NHEAD;
    const float* const xq = x + (size_t)bb * NTOK * XROW + hh * 64;

    // ---------------- S0 (the ONLY barrier phase): stage K, Ind, VT, T, Bm ----------------
    #pragma unroll
    for (int it = 0; it < 4; ++it) {              // K fragments: 208*8 = 1664 chunks
        int cid = tid + it * 512;
        if (cid < 1664) {
            int row = cid >> 3, cc = cid & 7;
            S8U t;
            #pragma unroll
            for (int e = 0; e < 8; ++e) t.u[e] = 0;
            if (row < NTOK) t.v = cvt8(xq + 640 + (size_t)row * XROW + cc * 8);
            *(short8*)(Ks + row * 128 + ((cc ^ (row & 7)) * 16)) = t.v;
        }
    }
    #pragma unroll
    for (int it = 0; it < 2; ++it) {              // Ind: 208*4 = 832 chunks
        int cid = tid + it * 512;
        if (cid < 832) {
            int row = cid >> 2, c4 = cid & 3;
            S8U t;
            #pragma unroll
            for (int e = 0; e < 8; ++e) {
                int c = c4 * 8 + e;               // logical col 64+c
                int on = 0;
                if (row < NTOK) {
                    if (c <= 14)      on = (row >= 1) && (row / 14 == c);
                    else if (c <= 28) on = (row >= 1) && (row % 14 == c - 15);
                    else if (c == 29) on = (row == 0);
                }
                t.u[e] = on ? 0x3F80 : 0;
            }
            *(short8*)(Inds + row * 64 + c4 * 16) = t.v;
        }
    }
    {                                             // VT slots 0..196: direct transposed load
        int d = tid & 63, grp = tid >> 6;
        #pragma unroll
        for (int it = 0; it < 4; ++it) {
            int jc = grp + it * 8;                // 8-slot chunk
            if (jc < 25) {
                int j0 = jc * 8;
                S8U t;
                #pragma unroll
                for (int e = 0; e < 8; ++e) {
                    int j = j0 + e;
                    t.u[e] = (j < NTOK) ? f2b(xq[1280 + (size_t)j * XROW + d]) : (unsigned short)0;
                }
                *(short8*)(VT + d * 512 + ((jc ^ (d & 7)) * 16)) = t.v;
            }
        }
        #pragma unroll
        for (int it = 0; it < 8; ++it) {          // VT slots 197..255: tables
            int r = grp + it * 8;
            if (r < 59) {
                float v;
                if (r == 0)       v = vtv[d] + vth[d];
                else if (r <= 29) v = vtv[r * 64 + d];
                else              v = vth[(r - 29) * 64 + d];
                int slot = 197 + r;
                int ch = (slot >> 3) ^ (d & 7);
                *(unsigned short*)(VT + d * 512 + ch * 16 + (slot & 7) * 2) = f2b(v);
            }
        }
    }
    {                                             // T: 64 rows x 8 chunks = 512 (one shot)
        int row = tid >> 3, cc = tid & 7;
        S8U t;
        #pragma unroll
        for (int e = 0; e < 8; ++e) {
            float v = 0.f;
            int dc = cc * 8 + e;
            if (row <= 29)      v = ktv[row * 64 + dc];
            else if (row <= 59) v = kth[(row - 30) * 64 + dc];
            else if (row == 60) v = ktv[dc] + kth[dc];
            t.u[e] = f2b(v);
        }
        *(short8*)(Ts + row * 128 + ((cc ^ (row & 7)) * 16)) = t.v;
    }
    #pragma unroll
    for (int it = 0; it < 2; ++it) {              // Bm: 32 rows x 32 chunks = 1024
        int cid = tid + it * 512;
        int row = cid >> 5, cc = cid & 31;
        S8U t;
        #pragma unroll
        for (int e = 0; e < 8; ++e) {
            int j = cc * 8 + e;
            int on = 0;
            if (j < NTOK) {
                if (row <= 14)      on = (j >= 1) && (j / 14 == row);
                else if (row == 15) on = (j == 0);
                else if (row <= 29) on = (j >= 1) && (j % 14 == row - 16);
            }
            t.u[e] = on ? 0x3F80 : 0;
        }
        *(short8*)(Bms + row * 512 + ((cc ^ (row & 7)) * 16)) = t.v;
    }
    __syncthreads();

    // ---------------- per-wave independent main loop (no further barriers) ----------------
    const int w  = tid >> 6, l = tid & 63;
    const int lm = l & 15,  lg = l >> 4;
    const f32x4 fzero = {0.f, 0.f, 0.f, 0.f};
    char* const Pw  = Pr + w * 8192;
    char* const Aug = Pw;                         // [16 rows][32 bf16=64B], alias P rows 0-1

    for (int rt = w; rt < 13; rt += 8) {
        // --- Q fragments straight from global (predicated) ---
        int qrow = rt * 16 + lm;
        const float* qp = xq + (size_t)qrow * XROW;
        short8 afq[2];
        #pragma unroll
        for (int s = 0; s < 2; ++s) {
            S8U t;
            #pragma unroll
            for (int e = 0; e < 8; ++e) t.u[e] = 0;
            if (qrow < NTOK) t.v = cvt8(qp + (s * 4 + lg) * 8);
            afq[s] = t.v;
        }
        // --- QD = Q . T^T ---
        f32x4 qd[4];
        #pragma unroll
        for (int n = 0; n < 4; ++n) qd[n] = fzero;
        #pragma unroll
        for (int s = 0; s < 2; ++s) {
            #pragma unroll
            for (int n = 0; n < 4; ++n) {
                int tr = n * 16 + lm;
                short8 tf = *(const short8*)(Ts + tr * 128 + (((s * 4 + lg) ^ (tr & 7)) * 16));
                qd[n] = MFMA(afq[s], tf, qd[n]);
            }
        }
        // --- zero aug buf, scatter qd into per-row window columns ---
        *(short8*)(Aug + l * 16) = short8{0,0,0,0,0,0,0,0};
        #pragma unroll
        for (int n = 0; n < 4; ++n) {
            int r = n * 16 + lm;
            #pragma unroll
            for (int reg = 0; reg < 4; ++reg) {
                int i = rt * 16 + lg * 4 + reg;
                if (i == 0 || i >= NTOK) continue;
                int col = -1;
                if (r <= 29)      { int c = r - 15 + i / 14; if (c >= 0 && c <= 14) col = c; }
                else if (r <= 59) { int c = r - 45 + i % 14; if (c >= 0 && c <= 13) col = 15 + c; }
                else if (r == 60) col = 29;
                if (col >= 0) {
                    int row = lg * 4 + reg;
                    *(unsigned short*)(Aug + row * 64 + (((col >> 3) ^ (row & 3)) * 16)
                                       + (col & 7) * 2) = f2b(qd[n][reg]);
                }
            }
        }
        if (rt == 0 && l == 12) {                 // row 0: constant bias q0.(ktv0+kth0)
            unsigned short v = f2b(qd[3][0]);
            #pragma unroll
            for (int c = 0; c <= 14; ++c) *(unsigned short*)(Aug + c * 2) = v;
            *(unsigned short*)(Aug + 29 * 2) = v;
        }
        // read aug A-fragment BEFORE any P writes clobber rows 0-1
        short8 af2 = *(const short8*)(Aug + lm * 64 + ((lg ^ (lm & 3)) * 16));

        // --- S = [Q|aug] . [K|Ind]^T  (K-dim 96) ---
        f32x4 acc[13];
        #pragma unroll
        for (int ct = 0; ct < 13; ++ct) acc[ct] = fzero;
        #pragma unroll
        for (int ct = 0; ct < 13; ++ct) {
            int r = ct * 16 + lm;
            short8 bf0 = *(const short8*)(Ks + r * 128 + ((lg ^ (r & 7)) * 16));
            acc[ct] = MFMA(afq[0], bf0, acc[ct]);
            short8 bf1 = *(const short8*)(Ks + r * 128 + (((4 + lg) ^ (r & 7)) * 16));
            acc[ct] = MFMA(afq[1], bf1, acc[ct]);
            short8 bfi = *(const short8*)(Inds + r * 64 + lg * 16);
            acc[ct] = MFMA(af2, bfi, acc[ct]);
        }
        // --- scale, mask cols >=197, softmax (row r: 16 cols across lm, fixed lg) ---
        #pragma unroll
        for (int ct = 0; ct < 13; ++ct) {
            acc[ct][0] *= 0.125f; acc[ct][1] *= 0.125f;
            acc[ct][2] *= 0.125f; acc[ct][3] *= 0.125f;
        }
        if (lm >= 5) {
            acc[12][0] = -INFINITY; acc[12][1] = -INFINITY;
            acc[12][2] = -INFINITY; acc[12][3] = -INFINITY;
        }
        #pragma unroll
        for (int reg = 0; reg < 4; ++reg) {
            float m = acc[0][reg];
            #pragma unroll
            for (int ct = 1; ct < 13; ++ct) m = fmaxf(m, acc[ct][reg]);
            m = fmaxf(m, __shfl_xor(m, 1)); m = fmaxf(m, __shfl_xor(m, 2));
            m = fmaxf(m, __shfl_xor(m, 4)); m = fmaxf(m, __shfl_xor(m, 8));
            float ss = 0.f;
            #pragma unroll
            for (int ct = 0; ct < 13; ++ct) {
                float p = __expf(acc[ct][reg] - m);
                acc[ct][reg] = p; ss += p;
            }
            ss += __shfl_xor(ss, 1); ss += __shfl_xor(ss, 2);
            ss += __shfl_xor(ss, 4); ss += __shfl_xor(ss, 8);
            float inv = 1.0f / ss;
            #pragma unroll
            for (int ct = 0; ct < 13; ++ct) acc[ct][reg] *= inv;
        }
        // --- write P'' (bf16, swizzled); masked cols are exact zeros ---
        #pragma unroll
        for (int ct = 0; ct < 13; ++ct) {
            int colc = ct * 16 + lm;
            #pragma unroll
            for (int reg = 0; reg < 4; ++reg) {
                int row = lg * 4 + reg;
                *(unsigned short*)(Pw + row * 512 + (((colc >> 3) ^ (row & 7)) * 16)
                                   + (colc & 7) * 2) = f2b(acc[ct][reg]);
            }
        }
        #pragma unroll
        for (int zz = 0; zz < 2; ++zz) {          // zero logical chunks 26..31 (slots 208..255)
            int z = l + zz * 64;
            if (z < 96) {
                int row = z / 6, ch = 26 + (z - row * 6);
                *(short8*)(Pw + row * 512 + ((ch ^ (row & 7)) * 16)) = short8{0,0,0,0,0,0,0,0};
            }
        }
        // --- bucket GEMM: BC = P . Bm^T  (K = 224) ---
        f32x4 bc[2]; bc[0] = fzero; bc[1] = fzero;
        #pragma unroll
        for (int s = 0; s < 7; ++s) {
            short8 pf = *(const short8*)(Pw + lm * 512 + (((s * 4 + lg) ^ (lm & 7)) * 16));
            #pragma unroll
            for (int n = 0; n < 2; ++n) {
                int tr = n * 16 + lm;
                short8 bmf = *(const short8*)(Bms + tr * 512 + (((s * 4 + lg) ^ (tr & 7)) * 16));
                bc[n] = MFMA(pf, bmf, bc[n]);
            }
        }
        // --- scatter buckets into P'' aug slots ---
        #pragma unroll
        for (int n = 0; n < 2; ++n) {
            int t = n * 16 + lm;
            #pragma unroll
            for (int reg = 0; reg < 4; ++reg) {
                int row = lg * 4 + reg;
                int i = rt * 16 + row;
                if (i == 0) {
                    if (t == 15)                  // sum(p)=1 -> coeff 1.0 on (vtv0+vth0)
                        *(unsigned short*)(Pw + (24 * 16) + (197 & 7) * 2) = 0x3F80;
                    continue;
                }
                if (i >= NTOK) continue;
                int slot = -1;
                if (t <= 14)      slot = 197 + (t + 15 - i / 14);
                else if (t == 15) slot = 197;
                else if (t <= 29) slot = 226 + ((t - 16) + 15 - i % 14);
                if (slot >= 0)
                    *(unsigned short*)(Pw + row * 512 + (((slot >> 3) ^ (row & 7)) * 16)
                                       + (slot & 7) * 2) = f2b(bc[n][reg]);
            }
        }
        // --- PV GEMM: O = P'' . V''  (K = 256) ---
        f32x4 o[4];
        #pragma unroll
        for (int nv = 0; nv < 4; ++nv) o[nv] = fzero;
        #pragma unroll
        for (int s = 0; s < 8; ++s) {
            short8 pf = *(const short8*)(Pw + lm * 512 + (((s * 4 + lg) ^ (lm & 7)) * 16));
            #pragma unroll
            for (int nv = 0; nv < 4; ++nv) {
                int vr = nv * 16 + lm;
                short8 vf = *(const short8*)(VT + vr * 512 + (((s * 4 + lg) ^ (vr & 7)) * 16));
                o[nv] = MFMA(pf, vf, o[nv]);
            }
        }
        // --- store ---
        #pragma unroll
        for (int reg = 0; reg < 4; ++reg) {
            int i = rt * 16 + lg * 4 + reg;
            if (i < NTOK) {
                float* dst = out + (size_t)bb * (NTOK * 640) + (size_t)i * 640 + hh * 64 + lm;
                #pragma unroll
                for (int nv = 0; nv < 4; ++nv) dst[nv * 16] = o[nv][reg];
            }
        }
    }
}

extern "C" void kernel_launch(void* const* d_in, const int* in_sizes, int n_in,
                              void* d_out, int out_size, void* d_ws, size_t ws_size,
                              hipStream_t stream) {
    const float* x   = (const float*)d_in[0];
    const float* ktv = (const float*)d_in[1];
    const float* kth = (const float*)d_in[2];
    const float* vtv = (const float*)d_in[3];
    const float* vth = (const float*)d_in[4];
    float* out = (float*)d_out;
    (void)hipFuncSetAttribute((const void*)attn_super,
                              hipFuncAttributeMaxDynamicSharedMemorySize, LDS_TOTAL);
    attn_super<<<dim3(64 * NHEAD), dim3(512), LDS_TOTAL, stream>>>(x, ktv, kth, vtv, vth, out);
}

// Round 6
// 211.221 us; speedup vs baseline: 1.3485x; 1.0133x over previous
//
#include <hip/hip_runtime.h>
#include <hip/hip_bf16.h>

#define NTOK 197
#define NHEAD 10
#define XROW 1920

typedef __attribute__((ext_vector_type(8))) short short8;
typedef __attribute__((ext_vector_type(4))) float f32x4;

union S8U { short8 v; unsigned short u[8]; unsigned int w[4]; };

__device__ __forceinline__ unsigned short f2b(float f) {
    union { float f; unsigned int i; } a; a.f = f;
    unsigned int r = a.i + 0x7FFFu + ((a.i >> 16) & 1u);
    return (unsigned short)(r >> 16);
}

__device__ __forceinline__ short8 cvt8(const float* p) {
    const float4* s4 = (const float4*)p;
    float4 f0 = s4[0], f1 = s4[1];
    S8U t;
    t.u[0] = f2b(f0.x); t.u[1] = f2b(f0.y); t.u[2] = f2b(f0.z); t.u[3] = f2b(f0.w);
    t.u[4] = f2b(f1.x); t.u[5] = f2b(f1.y); t.u[6] = f2b(f1.z); t.u[7] = f2b(f1.w);
    return t.v;
}

// LDS (bytes):
//  K     [208 rows][128B]  K fragments, chunk' = c ^ (row&7)           26624
//  Ind   [208 rows][ 64B]  indicator cols (j/14|j%14|j==0), c^(row&3)  13312
//  VT    [64 d   ][512B]   V^T slots j 0..199 staged; chunk'=c^(d&7)   32768
//  VtabT [64 d   ][128B]   rel-V tables T^T: r0..29 vtv, 30..58 vth,
//                          59 vtv0+vth0, 60..63 zero; chunk'=c^(d&7)    8192
//  Bm    [32 rows][512B]   bucket indicators, chunk'=c^(row&7)         16384
//  SCR   16 waves x 4096B  per-wave scratch: augS (1KB) -> P two-phase
//                          (4KB) -> augV (2KB); chunk swizzles ^(row&K) 65536
#define OFF_K    0
#define OFF_IND  26624
#define OFF_VT   39936
#define OFF_VTAB 72704
#define OFF_BM   80896
#define OFF_SCR  97280
#define LDS_TOTAL 162816

#define MFMA(a, b, c) __builtin_amdgcn_mfma_f32_16x16x32_bf16(a, b, c, 0, 0, 0)

__global__ __launch_bounds__(1024)
void attn_super(const float* __restrict__ x,
                const float* __restrict__ ktv, const float* __restrict__ kth,
                const float* __restrict__ vtv, const float* __restrict__ vth,
                float* __restrict__ out)
{
    extern __shared__ char smem[];
    char* const Ks    = smem + OFF_K;
    char* const Inds  = smem + OFF_IND;
    char* const VT    = smem + OFF_VT;
    char* const Vtab  = smem + OFF_VTAB;
    char* const Bms   = smem + OFF_BM;
    char* const Scr   = smem + OFF_SCR;

    const int tid = threadIdx.x;
    const int bb = blockIdx.x / NHEAD;
    const int hh = blockIdx.x - bb * NHEAD;
    const float* const xq = x + (size_t)bb * NTOK * XROW + hh * 64;

    // ---------------- staging (single barrier) ----------------
    #pragma unroll
    for (int it = 0; it < 2; ++it) {              // K: 208*8 = 1664 chunks
        int cid = tid + it * 1024;
        if (cid < 1664) {
            int row = cid >> 3, cc = cid & 7;
            S8U t;
            #pragma unroll
            for (int e = 0; e < 8; ++e) t.u[e] = 0;
            if (row < NTOK) t.v = cvt8(xq + 640 + (size_t)row * XROW + cc * 8);
            *(short8*)(Ks + row * 128 + ((cc ^ (row & 7)) * 16)) = t.v;
        }
    }
    if (tid < 832) {                              // Ind: 208*4 chunks
        int row = tid >> 2, c4 = tid & 3;
        S8U t;
        #pragma unroll
        for (int e = 0; e < 8; ++e) {
            int c = c4 * 8 + e;                   // logical col 64+c
            int on = 0;
            if (row < NTOK) {
                if (c <= 14)      on = (row >= 1) && (row / 14 == c);
                else if (c <= 28) on = (row >= 1) && (row % 14 == c - 15);
                else if (c == 29) on = (row == 0);
            }
            t.u[e] = on ? 0x3F80 : 0;
        }
        *(short8*)(Inds + row * 64 + ((c4 ^ (row & 3)) * 16)) = t.v;
    }
    {
        int d = tid & 63, grp = tid >> 6;
        #pragma unroll
        for (int it = 0; it < 2; ++it) {          // VT slots 0..199 (25 chunks)
            int jc = grp + it * 16;
            if (jc < 25) {
                int j0 = jc * 8;
                S8U t;
                #pragma unroll
                for (int e = 0; e < 8; ++e) {
                    int j = j0 + e;
                    t.u[e] = (j < NTOK) ? f2b(xq[1280 + (size_t)j * XROW + d]) : (unsigned short)0;
                }
                *(short8*)(VT + d * 512 + ((jc ^ (d & 7)) * 16)) = t.v;
            }
        }
        #pragma unroll
        for (int it = 0; it < 4; ++it) {          // VtabT: 64 table rows
            int r = grp + it * 16;
            float v = 0.f;
            if (r <= 29)      v = vtv[r * 64 + d];
            else if (r <= 58) v = vth[(r - 29) * 64 + d];
            else if (r == 59) v = vtv[d] + vth[d];
            *(unsigned short*)(Vtab + d * 128 + (((r >> 3) ^ (d & 7)) * 16)
                               + (r & 7) * 2) = f2b(v);
        }
    }
    {                                             // Bm: 32*32 = 1024 chunks
        int row = tid >> 5, cc = tid & 31;
        S8U t;
        #pragma unroll
        for (int e = 0; e < 8; ++e) {
            int j = cc * 8 + e;
            int on = 0;
            if (j < NTOK) {
                if (row <= 14)      on = (j >= 1) && (j / 14 == row);
                else if (row == 15) on = (j == 0);
                else if (row <= 29) on = (j >= 1) && (j % 14 == row - 16);
            }
            t.u[e] = on ? 0x3F80 : 0;
        }
        *(short8*)(Bms + row * 512 + ((cc ^ (row & 7)) * 16)) = t.v;
    }
    __syncthreads();

    // ---------------- one tile per wave ----------------
    const int w = tid >> 6;
    if (w >= 13) return;
    const int rt = w;
    const int l = tid & 63, lm = l & 15, lg = l >> 4;
    const f32x4 fzero = {0.f, 0.f, 0.f, 0.f};
    char* const ScrW = Scr + w * 4096;

    // --- Q fragments from global (predicated rows >=197) ---
    const int qrow = rt * 16 + lm;
    const float* qp = xq + (size_t)qrow * XROW;
    short8 afq[2];
    #pragma unroll
    for (int s = 0; s < 2; ++s) {
        S8U t;
        #pragma unroll
        for (int e = 0; e < 8; ++e) t.u[e] = 0;
        if (qrow < NTOK) t.v = cvt8(qp + (s * 4 + lg) * 8);
        afq[s] = t.v;
    }

    // --- QD = Q . T^T, T rows from global (L1-hot) ---
    f32x4 qd[4];
    #pragma unroll
    for (int n = 0; n < 4; ++n) qd[n] = fzero;
    #pragma unroll
    for (int s = 0; s < 2; ++s) {
        int k0 = s * 32 + lg * 8;
        #pragma unroll
        for (int n = 0; n < 4; ++n) {
            int tr = n * 16 + lm;
            S8U t;
            if (tr >= 61) {
                #pragma unroll
                for (int e = 0; e < 8; ++e) t.u[e] = 0;
            } else if (tr == 60) {
                #pragma unroll
                for (int e = 0; e < 8; ++e) t.u[e] = f2b(ktv[k0 + e] + kth[k0 + e]);
            } else {
                const float* tp = (tr <= 29) ? (ktv + tr * 64) : (kth + (tr - 30) * 64);
                t.v = cvt8(tp + k0);
            }
            qd[n] = MFMA(afq[s], t.v, qd[n]);
        }
    }

    // --- augS: zero 1KB, scatter qd windows, read aug A-fragment ---
    *(short8*)(ScrW + l * 16) = short8{0,0,0,0,0,0,0,0};
    #pragma unroll
    for (int n = 0; n < 4; ++n) {
        int r = n * 16 + lm;
        #pragma unroll
        for (int reg = 0; reg < 4; ++reg) {
            int i = rt * 16 + lg * 4 + reg;
            if (i == 0 || i >= NTOK) continue;
            int col = -1;
            if (r <= 29)      { int c = r - 15 + i / 14; if (c >= 0 && c <= 14) col = c; }
            else if (r <= 59) { int c = r - 45 + i % 14; if (c >= 0 && c <= 13) col = 15 + c; }
            else if (r == 60) col = 29;
            if (col >= 0) {
                int row = lg * 4 + reg;
                *(unsigned short*)(ScrW + row * 64 + (((col >> 3) ^ (row & 3)) * 16)
                                   + (col & 7) * 2) = f2b(qd[n][reg]);
            }
        }
    }
    if (rt == 0 && l == 12) {                     // row 0: const bias q0.(ktv0+kth0)
        unsigned short v = f2b(qd[3][0]);
        #pragma unroll
        for (int c = 0; c <= 14; ++c) *(unsigned short*)(ScrW + c * 2) = v;
        *(unsigned short*)(ScrW + 29 * 2) = v;
    }
    short8 af2 = *(const short8*)(ScrW + lm * 64 + ((lg ^ (lm & 3)) * 16));

    // --- S^T = [K|Ind] . [Q|aug]^T : lane holds q-row i=lm, j=ct*16+lg*4+reg ---
    f32x4 acc[13];
    #pragma unroll
    for (int ct = 0; ct < 13; ++ct) acc[ct] = fzero;
    #pragma unroll
    for (int ct = 0; ct < 13; ++ct) {
        int jr = ct * 16 + lm;
        short8 bf0 = *(const short8*)(Ks + jr * 128 + ((lg ^ (jr & 7)) * 16));
        acc[ct] = MFMA(bf0, afq[0], acc[ct]);
        short8 bf1 = *(const short8*)(Ks + jr * 128 + (((4 + lg) ^ (jr & 7)) * 16));
        acc[ct] = MFMA(bf1, afq[1], acc[ct]);
        short8 bfi = *(const short8*)(Inds + jr * 64 + ((lg ^ (jr & 3)) * 16));
        acc[ct] = MFMA(bfi, af2, acc[ct]);
    }

    // --- scale, mask j>=197, softmax over j (in-lane + xor16/32) ---
    #pragma unroll
    for (int ct = 0; ct < 13; ++ct) {
        acc[ct][0] *= 0.125f; acc[ct][1] *= 0.125f;
        acc[ct][2] *= 0.125f; acc[ct][3] *= 0.125f;
    }
    #pragma unroll
    for (int reg = 0; reg < 4; ++reg)
        if (lg * 4 + reg >= 5) acc[12][reg] = -INFINITY;
    float m = -INFINITY;
    #pragma unroll
    for (int ct = 0; ct < 13; ++ct) {
        m = fmaxf(m, fmaxf(fmaxf(acc[ct][0], acc[ct][1]), fmaxf(acc[ct][2], acc[ct][3])));
    }
    m = fmaxf(m, __shfl_xor(m, 16)); m = fmaxf(m, __shfl_xor(m, 32));
    float ss = 0.f;
    #pragma unroll
    for (int ct = 0; ct < 13; ++ct) {
        #pragma unroll
        for (int reg = 0; reg < 4; ++reg) {
            float p = __expf(acc[ct][reg] - m);
            acc[ct][reg] = p; ss += p;
        }
    }
    ss += __shfl_xor(ss, 16); ss += __shfl_xor(ss, 32);
    float inv = 1.0f / ss;

    // --- pack P to bf16 pairs (consecutive j) ---
    unsigned int pp[13][2];
    #pragma unroll
    for (int ct = 0; ct < 13; ++ct) {
        pp[ct][0] = (unsigned int)f2b(acc[ct][0] * inv) |
                    ((unsigned int)f2b(acc[ct][1] * inv) << 16);
        pp[ct][1] = (unsigned int)f2b(acc[ct][2] * inv) |
                    ((unsigned int)f2b(acc[ct][3] * inv) << 16);
    }

    // --- P scratch two-phase: build 7 A-fragments (k-steps of 32 j) ---
    short8 af_p[7];
    #pragma unroll
    for (int ct = 0; ct < 8; ++ct) {              // phase 1: j 0..127
        int ch = ct * 2 + (lg >> 1);
        char* a = ScrW + lm * 256 + ((ch ^ (lm & 7)) * 16) + (lg & 1) * 8;
        ((unsigned int*)a)[0] = pp[ct][0]; ((unsigned int*)a)[1] = pp[ct][1];
    }
    #pragma unroll
    for (int s = 0; s < 4; ++s)
        af_p[s] = *(const short8*)(ScrW + lm * 256 + (((s * 4 + lg) ^ (lm & 7)) * 16));
    #pragma unroll
    for (int ct = 8; ct < 13; ++ct) {             // phase 2: j 128..207 at base
        int ch = (ct - 8) * 2 + (lg >> 1);
        char* a = ScrW + lm * 256 + ((ch ^ (lm & 7)) * 16) + (lg & 1) * 8;
        ((unsigned int*)a)[0] = pp[ct][0]; ((unsigned int*)a)[1] = pp[ct][1];
    }
    if (lg < 2)                                   // zero j 208..223 (chunks 10,11)
        *(short8*)(ScrW + lm * 256 + (((10 + lg) ^ (lm & 7)) * 16)) = short8{0,0,0,0,0,0,0,0};
    #pragma unroll
    for (int s = 4; s < 7; ++s)
        af_p[s] = *(const short8*)(ScrW + lm * 256 + ((((s - 4) * 4 + lg) ^ (lm & 7)) * 16));

    // --- bucket GEMM: BC = P . Bm^T (K = 224) ---
    f32x4 bc[2]; bc[0] = fzero; bc[1] = fzero;
    #pragma unroll
    for (int s = 0; s < 7; ++s) {
        #pragma unroll
        for (int n = 0; n < 2; ++n) {
            int tr = n * 16 + lm;
            short8 bmf = *(const short8*)(Bms + tr * 512 + (((s * 4 + lg) ^ (tr & 7)) * 16));
            bc[n] = MFMA(af_p[s], bmf, bc[n]);
        }
    }

    // --- augV: zero 2KB, scatter bucket coefs at ABSOLUTE table cols ---
    *(short8*)(ScrW + l * 32) = short8{0,0,0,0,0,0,0,0};
    *(short8*)(ScrW + l * 32 + 16) = short8{0,0,0,0,0,0,0,0};
    #pragma unroll
    for (int n = 0; n < 2; ++n) {
        int t = n * 16 + lm;
        #pragma unroll
        for (int reg = 0; reg < 4; ++reg) {
            int row = lg * 4 + reg;
            int i = rt * 16 + row;
            if (i == 0) {
                if (t == 15)                      // sum(p)=1 -> 1.0 on (vtv0+vth0)
                    *(unsigned short*)(ScrW + (((59 >> 3) ^ 0) * 16) + (59 & 7) * 2) = 0x3F80;
                continue;
            }
            if (i >= NTOK) continue;
            int col = -1;
            if (t <= 14)      col = t + 15 - i / 14;             // vtv row 1..29
            else if (t == 15) col = 59;                          // vtv0+vth0
            else              col = 29 + (t - 16) + 15 - i % 14; // vth row 29+ih
            if (col >= 0)
                *(unsigned short*)(ScrW + row * 128 + (((col >> 3) ^ (row & 7)) * 16)
                                   + (col & 7) * 2) = f2b(bc[n][reg]);
        }
    }
    short8 ag[2];
    #pragma unroll
    for (int s = 0; s < 2; ++s)
        ag[s] = *(const short8*)(ScrW + lm * 128 + (((s * 4 + lg) ^ (lm & 7)) * 16));

    // --- PV: O = P.V^T (7 reg k-steps) + Aug.Vtab (2 k-steps) ---
    f32x4 o[4];
    #pragma unroll
    for (int nv = 0; nv < 4; ++nv) o[nv] = fzero;
    #pragma unroll
    for (int s = 0; s < 7; ++s) {
        #pragma unroll
        for (int nv = 0; nv < 4; ++nv) {
            int d = nv * 16 + lm;
            short8 vf = *(const short8*)(VT + d * 512 + (((s * 4 + lg) ^ (d & 7)) * 16));
            o[nv] = MFMA(af_p[s], vf, o[nv]);
        }
    }
    #pragma unroll
    for (int s = 0; s < 2; ++s) {
        #pragma unroll
        for (int nv = 0; nv < 4; ++nv) {
            int d = nv * 16 + lm;
            short8 vtf = *(const short8*)(Vtab + d * 128 + (((s * 4 + lg) ^ (d & 7)) * 16));
            o[nv] = MFMA(ag[s], vtf, o[nv]);
        }
    }

    // --- store ---
    #pragma unroll
    for (int reg = 0; reg < 4; ++reg) {
        int i = rt * 16 + lg * 4 + reg;
        if (i < NTOK) {
            float* dst = out + (size_t)bb * (NTOK * 640) + (size_t)i * 640 + hh * 64 + lm;
            #pragma unroll
            for (int nv = 0; nv < 4; ++nv) dst[nv * 16] = o[nv][reg];
        }
    }
}

extern "C" void kernel_launch(void* const* d_in, const int* in_sizes, int n_in,
                              void* d_out, int out_size, void* d_ws, size_t ws_size,
                              hipStream_t stream) {
    const float* x   = (const float*)d_in[0];
    const float* ktv = (const float*)d_in[1];
    const float* kth = (const float*)d_in[2];
    const float* vtv = (const float*)d_in[3];
    const float* vth = (const float*)d_in[4];
    float* out = (float*)d_out;
    (void)hipFuncSetAttribute((const void*)attn_super,
                              hipFuncAttributeMaxDynamicSharedMemorySize, LDS_TOTAL);
    attn_super<<<dim3(64 * NHEAD), dim3(1024), LDS_TOTAL, stream>>>(x, ktv, kth, vtv, vth, out);
}